// Round 1
// 1642.958 us; speedup vs baseline: 1.1896x; 1.1896x over previous
//
#include <hip/hip_runtime.h>

#define DD 64

typedef float v2f __attribute__((ext_vector_type(2)));
typedef float v4f __attribute__((ext_vector_type(4)));

// Build symmetric coupling matrix M (64x64) from packed strict-lower-triangle Q.
__global__ void build_M_kernel(const float* __restrict__ Q, float* __restrict__ M) {
    int idx = blockIdx.x * 256 + threadIdx.x;
    if (idx < DD * DD) {
        int r = idx >> 6;
        int c = idx & 63;
        float v = 0.0f;
        if (r > c)      v = Q[(r * (r - 1)) / 2 + c];
        else if (c > r) v = Q[(c * (c - 1)) / 2 + r];
        M[idx] = v;
    }
}

// ---- one Gauss-Seidel step, K compile-time => all indices constant ----
// x: 32 float2 pairs (coord 2i, 2i+1). uc: 8 float4 of u*k2 for this half-sweep.
template<int K>
__device__ __forceinline__ void gs_step(v2f (&x)[32],
        const float* __restrict__ M, const float* __restrict__ delta,
        float k2, const v4f (&uc)[8])
{
    const v2f* __restrict__ Mr = (const v2f*)(M + K * DD);
    v2f a0 = {0.f, 0.f}, a1 = {0.f, 0.f}, a2 = {0.f, 0.f}, a3 = {0.f, 0.f};
#pragma unroll
    for (int j = 0; j < 32; j += 4) {
        a0 = __builtin_elementwise_fma(Mr[j + 0], x[j + 0], a0);   // v_pk_fma_f32
        a1 = __builtin_elementwise_fma(Mr[j + 1], x[j + 1], a1);
        a2 = __builtin_elementwise_fma(Mr[j + 2], x[j + 2], a2);
        a3 = __builtin_elementwise_fma(Mr[j + 3], x[j + 3], a3);
    }
    v2f s = (a0 + a1) + (a2 + a3);
    float alpha = (s[0] + s[1]) + delta[K];
    // sigmoid(2a) = 1 / (1 + 2^(a * -2*log2(e))); branchless, |alpha| <~ 2 so no overflow
    const float NEG2LOG2E = -2.8853900817779268f;
    float sig = __builtin_amdgcn_rcpf(1.0f + exp2f(alpha * NEG2LOG2E));
    // tanh(c*(sig - u)) = 1 - 2/(1 + 2^((sig-u)*2c*log2(e))); uc holds u*2c*log2(e)
    float r = __builtin_amdgcn_rcpf(1.0f + exp2f(fmaf(sig, k2, -uc[(K & 31) >> 2][K & 3])));
    x[K >> 1][K & 1] = fmaf(-2.0f, r, 1.0f);
}

template<int K, int KEND>
struct Steps {
    static __device__ __forceinline__ void run(v2f (&x)[32],
            const float* __restrict__ M, const float* __restrict__ delta,
            float k2, const v4f (&uc)[8]) {
        gs_step<K>(x, M, delta, k2, uc);
        Steps<K + 1, KEND>::run(x, M, delta, k2, uc);
    }
};
template<int KEND>
struct Steps<KEND, KEND> {
    static __device__ __forceinline__ void run(v2f (&)[32],
            const float*, const float*, float, const v4f (&)[8]) {}
};

// Half-sweep (32 coords): load this thread's 128-byte u line, pre-scale by k2, run steps.
template<int H>  // H = 0 or 1
__device__ __forceinline__ void half_sweep(v2f (&x)[32],
        const float* __restrict__ M, const float* __restrict__ delta,
        float k2, const float* __restrict__ ub)
{
    const v4f* __restrict__ up = (const v4f*)(ub + H * 32);
    v4f uc[8];
#pragma unroll
    for (int i = 0; i < 8; ++i) uc[i] = up[i] * k2;
    Steps<H * 32, H * 32 + 32>::run(x, M, delta, k2, uc);
}

// ---- energy term for row K (packed dot) ----
template<int K>
__device__ __forceinline__ float energy_step(const v2f (&x)[32],
        const float* __restrict__ M, const float* __restrict__ delta)
{
    const v2f* __restrict__ Mr = (const v2f*)(M + K * DD);
    v2f a0 = {0.f, 0.f}, a1 = {0.f, 0.f}, a2 = {0.f, 0.f}, a3 = {0.f, 0.f};
#pragma unroll
    for (int j = 0; j < 32; j += 4) {
        a0 = __builtin_elementwise_fma(Mr[j + 0], x[j + 0], a0);
        a1 = __builtin_elementwise_fma(Mr[j + 1], x[j + 1], a1);
        a2 = __builtin_elementwise_fma(Mr[j + 2], x[j + 2], a2);
        a3 = __builtin_elementwise_fma(Mr[j + 3], x[j + 3], a3);
    }
    v2f s = (a0 + a1) + (a2 + a3);
    float dot = s[0] + s[1];
    return fmaf(0.5f, dot, delta[K]) * x[K >> 1][K & 1];
}

template<int K, int KEND>
struct EnergyAcc {
    static __device__ __forceinline__ float run(const v2f (&x)[32],
            const float* __restrict__ M, const float* __restrict__ delta) {
        return energy_step<K>(x, M, delta) + EnergyAcc<K + 1, KEND>::run(x, M, delta);
    }
};
template<int KEND>
struct EnergyAcc<KEND, KEND> {
    static __device__ __forceinline__ float run(const v2f (&)[32],
            const float*, const float*) { return 0.0f; }
};

__global__ __launch_bounds__(256, 4) void ising_main(
    const float* __restrict__ M,       // 64x64 symmetric, diag 0 (in d_ws)
    const float* __restrict__ delta,   // 64
    const float* __restrict__ x0,      // B*64
    const float* __restrict__ u,       // L*B*64
    const int* __restrict__ n_layers_p,
    const int* __restrict__ const_p,
    float* __restrict__ out,           // B*64 (z) then B (energy)
    int B)
{
    const int b = blockIdx.x * 256 + threadIdx.x;
    const int L = n_layers_p[0];
    const float c = (float)const_p[0];
    const float k2 = 2.0f * c * 1.4426950408889634f;   // 2*c*log2(e)

    // ---- x0 load: 16x float4, thread-contiguous 256 B ----
    v2f x[32];
    {
        const v4f* __restrict__ xs = (const v4f*)(x0 + (size_t)b * DD);
#pragma unroll
        for (int i = 0; i < 16; ++i) {
            v4f v = xs[i];
            x[2 * i]     = (v2f){v[0], v[1]};
            x[2 * i + 1] = (v2f){v[2], v[3]};
        }
    }

    // ---- sweeps: no LDS, no barriers ----
    for (int l = 0; l < L; ++l) {
        const float* __restrict__ ub = u + ((size_t)l * B + b) * (size_t)DD;
        half_sweep<0>(x, M, delta, k2, ub);
        half_sweep<1>(x, M, delta, k2, ub);
    }

    // ---- energy ----
    float energy = EnergyAcc<0, DD>::run(x, M, delta);

    // ---- z store: 16x float4 ----
    {
        v4f* __restrict__ zd = (v4f*)(out + (size_t)b * DD);
#pragma unroll
        for (int i = 0; i < 16; ++i) {
            zd[i] = (v4f){x[2 * i][0], x[2 * i][1], x[2 * i + 1][0], x[2 * i + 1][1]};
        }
    }
    out[(size_t)B * DD + b] = energy;
}

extern "C" void kernel_launch(void* const* d_in, const int* in_sizes, int n_in,
                              void* d_out, int out_size, void* d_ws, size_t ws_size,
                              hipStream_t stream) {
    // setup_inputs order: inputs(B,1)[unused], Q(2016), delta(64), x0(B*64),
    // u(L*B*64), n_layers(1 int), const(1 int)
    const float* Q     = (const float*)d_in[1];
    const float* delta = (const float*)d_in[2];
    const float* x0    = (const float*)d_in[3];
    const float* u     = (const float*)d_in[4];
    const int*   nl    = (const int*)d_in[5];
    const int*   cc    = (const int*)d_in[6];
    float* M = (float*)d_ws;  // 16 KB scratch
    int B = in_sizes[3] / DD;

    build_M_kernel<<<(DD * DD + 255) / 256, 256, 0, stream>>>(Q, M);
    ising_main<<<B / 256, 256, 0, stream>>>(M, delta, x0, u, nl, cc,
                                            (float*)d_out, B);
}